// Round 9
// baseline (285.929 us; speedup 1.0000x reference)
//
#include <hip/hip_runtime.h>

// ---------- types ----------
using bf16x8 = __attribute__((ext_vector_type(8))) short;
using v8bf   = __attribute__((ext_vector_type(8))) __bf16;
using f32x4  = __attribute__((ext_vector_type(4))) float;
using u32x2  = __attribute__((ext_vector_type(2))) unsigned;
using bf16x2 = __attribute__((ext_vector_type(2))) __bf16;

typedef const __attribute__((address_space(1))) void GASV;
typedef __attribute__((address_space(3))) void LASV;

template <typename V>
__device__ __forceinline__ auto mfma_bf16_impl(V a, V b, f32x4 c, int)
    -> decltype(__builtin_amdgcn_mfma_f32_16x16x32_bf16(a, b, c, 0, 0, 0)) {
  return __builtin_amdgcn_mfma_f32_16x16x32_bf16(a, b, c, 0, 0, 0);
}
template <typename V>
__device__ __forceinline__ f32x4 mfma_bf16_impl(V a, V b, f32x4 c, long) {
  return __builtin_amdgcn_mfma_f32_16x16x32_bf16(
      __builtin_bit_cast(v8bf, a), __builtin_bit_cast(v8bf, b), c, 0, 0, 0);
}
__device__ __forceinline__ f32x4 MFMA(bf16x8 a, bf16x8 b, f32x4 c) {
  return mfma_bf16_impl(a, b, c, 0);
}

__device__ __forceinline__ void async_lds16(const void* g, void* l) {
  __builtin_amdgcn_global_load_lds((GASV*)g, (LASV*)l, 16, 0, 0);
}

__device__ __forceinline__ unsigned short f2bf(float x) {
  unsigned u = __float_as_uint(x);
  u = u + 0x7fffu + ((u >> 16) & 1u);
  return (unsigned short)(u >> 16);
}

// pack two floats to packed bf16 (RNE); compiler emits v_cvt_pk_bf16_f32
__device__ __forceinline__ unsigned pack_bf2(float lo, float hi) {
  bf16x2 t;
  t[0] = (__bf16)lo;
  t[1] = (__bf16)hi;
  return __builtin_bit_cast(unsigned, t);
}

#define LOG2E 1.4426950408889634f
#define SOFT_OFF 14.0f  // fixed softmax offset (exp2 domain)

// ---------- fused prep: x->bf16 cast (bid<4096) + W transposes (bid>=4096) ----
// Wq (z==1) pre-scaled by LOG2E/8 so attention QK^T lands in exp2 domain.
__global__ __launch_bounds__(256) void k_prep(
    const float4* __restrict__ x, ushort4* __restrict__ xb,
    const float* __restrict__ w0, const float* __restrict__ w1,
    const float* __restrict__ w2, const float* __restrict__ w3,
    const float* __restrict__ w4, unsigned short* __restrict__ out) {
  const int bid = blockIdx.x, tid = threadIdx.x;
  if (bid < 4096) {
    const int i = bid * 256 + tid;
    float4 v = x[i];
    ushort4 p;
    p.x = f2bf(v.x); p.y = f2bf(v.y); p.z = f2bf(v.z); p.w = f2bf(v.w);
    xb[i] = p;
    return;
  }
  __shared__ float t[32][33];
  const int tb = bid - 4096;
  const int z = tb >> 10;
  const float* W = (z == 0) ? w0 : (z == 1) ? w1 : (z == 2) ? w2 : (z == 3) ? w3 : w4;
  const float sc = (z == 1) ? (LOG2E / 8.0f) : 1.0f;
  unsigned short* o = out + (size_t)z * (1u << 20);
  const int bx = (tb & 31) * 32, by = ((tb >> 5) & 31) * 32;
  const int tx = tid & 31, ty = tid >> 5;  // 32 x 8
#pragma unroll
  for (int i = 0; i < 4; ++i)
    t[ty + i * 8][tx] = W[(size_t)(by + ty + i * 8) * 1024 + bx + tx];
  __syncthreads();
#pragma unroll
  for (int i = 0; i < 4; ++i)
    o[(size_t)(bx + ty + i * 8) * 1024 + by + tx] = f2bf(t[tx][ty + i * 8] * sc);
}

// ---------- templated NT GEMM core, BK=64 (K=1024): tile (MI*32)x(NI*32) ----
// 32 MFMAs per barrier pair; 128B rows, 16B chunk XOR-swizzled with row&7.
// (Used by k_gemm_logits / k_gemm_out.)
template <int MI, int NI>
__device__ __forceinline__ void gemm_core_t(const unsigned short* __restrict__ A,
                                            const unsigned short* __restrict__ Bt,
                                            unsigned short* ldsA,
                                            unsigned short* ldsB,
                                            f32x4 acc[MI][NI]) {
  const int tid = threadIdx.x;
  const int w = tid >> 6, lane = tid & 63;
  const int lane15 = lane & 15, quad = lane >> 4;
  const int wm = w >> 1, wn = w & 1;
  for (int ko = 0; ko < 16; ++ko) {
    __syncthreads();
#pragma unroll
    for (int i = 0; i < MI; ++i) {
      const int p = i * 256 + tid;
      const int r = p >> 3, cc = (p & 7) ^ (r & 7);
      async_lds16(A + r * 1024 + ko * 64 + cc * 8, ldsA + (i * 256 + w * 64) * 8);
    }
#pragma unroll
    for (int i = 0; i < NI; ++i) {
      const int p = i * 256 + tid;
      const int r = p >> 3, cc = (p & 7) ^ (r & 7);
      async_lds16(Bt + r * 1024 + ko * 64 + cc * 8, ldsB + (i * 256 + w * 64) * 8);
    }
    __syncthreads();
    bf16x8 af[MI][2], bfr[NI][2];
#pragma unroll
    for (int t = 0; t < MI; ++t) {
      const int row = wm * (MI * 16) + t * 16 + lane15;
#pragma unroll
      for (int h = 0; h < 2; ++h)
        af[t][h] = *(const bf16x8*)&ldsA[row * 64 + (((h * 4 + quad) ^ (row & 7)) << 3)];
    }
#pragma unroll
    for (int t = 0; t < NI; ++t) {
      const int row = wn * (NI * 16) + t * 16 + lane15;
#pragma unroll
      for (int h = 0; h < 2; ++h)
        bfr[t][h] = *(const bf16x8*)&ldsB[row * 64 + (((h * 4 + quad) ^ (row & 7)) << 3)];
    }
#pragma unroll
    for (int mi = 0; mi < MI; ++mi)
#pragma unroll
      for (int ni = 0; ni < NI; ++ni) {
        acc[mi][ni] = MFMA(af[mi][0], bfr[ni][0], acc[mi][ni]);
        acc[mi][ni] = MFMA(af[mi][1], bfr[ni][1], acc[mi][ni]);
      }
  }
}

#define GEMM_PROLOGUE(MI_, NI_)                                      \
  __shared__ unsigned short ldsA[(MI_)*32 * 64];                     \
  __shared__ unsigned short ldsB[(NI_)*32 * 64];                     \
  f32x4 acc[MI_][NI_];                                               \
  {                                                                  \
    f32x4 z_ = {0.f, 0.f, 0.f, 0.f};                                 \
    for (int i_ = 0; i_ < (MI_); ++i_)                               \
      for (int j_ = 0; j_ < (NI_); ++j_) acc[i_][j_] = z_;           \
  }

#define GEMM_EPI_IDX(MI_, NI_)                                       \
  const int tid = threadIdx.x, w = tid >> 6, lane = tid & 63;        \
  const int lane15 = lane & 15, quad = lane >> 4;                    \
  const int wm = w >> 1, wn = w & 1;                                 \
  const int r0 = tm + wm * ((MI_)*16) + quad * 4;                    \
  const int c0 = tn + wn * ((NI_)*16) + lane15;

// ---------- qkv+pre GEMM: 256x128 tile, zero-LDS, zero-barrier -------------
// R8 post-mortem: keeping B's staging barrier made __syncthreads (implicit
// vmcnt(0)) drain the just-issued A-register prefetches -> serialized. Fix:
// BOTH operands load direct from global to VGPRs (B's fragment pattern is
// the same 16-row x 64B-segment shape as A's), LDS and all barriers deleted.
// Each wave is independent pure-register dataflow: compiler emits counted
// vmcnt and pipelines the 2-deep af/bf ping-pong freely (the m114 TLP + ILP
// mechanism with nothing to defeat it). Dup traffic (A x2, B x4) stays in
// L2: ~4MB/CU over the kernel ≈ 13us L2-BW floor. launch_bounds(512,2):
// acc in AGPRs (64) + ~64 frag VGPRs, no spill; 8 waves/CU, 2/SIMD.
// z: 0=pre 1=q 2=k -> C^T (A=W,B=x, M=out,N=seq); z=3 v: A=x,B=W (M=seq).
__global__ __launch_bounds__(512, 2) void k_gemm_qkvpre(
    const unsigned short* __restrict__ xb, const unsigned short* __restrict__ wt,
    const float* __restrict__ bpre, unsigned short* __restrict__ pre,
    unsigned short* __restrict__ qb, unsigned short* __restrict__ kb,
    unsigned short* __restrict__ vt) {
  const int bid = blockIdx.x;
  const int xcd = bid & 7, idx = bid >> 3;  // idx 0..63 per xcd
  const int z = xcd >> 1, half = xcd & 1;
  int tm, tn;
  if (z == 3) {  // v: M = seq (4096), N = out (1024)
    tm = half * 2048 + (idx >> 3) * 256;  // 8 seq-tiles per half
    tn = (idx & 7) * 128;                 // 8 out-tiles
  } else {       // pre/q/k: M = out (1024), N = seq (4096)
    tm = (idx >> 4) * 256;                // 4 out-tiles
    tn = half * 2048 + (idx & 15) * 128;  // 16 seq-tiles per half
  }
  const unsigned short* At =
      (z == 3) ? xb + (size_t)tm * 1024
               : wt + (size_t)z * (1u << 20) + (size_t)tm * 1024;
  const unsigned short* Bt_ =
      (z == 3) ? wt + (size_t)3 * (1u << 20) + (size_t)tn * 1024
               : xb + (size_t)tn * 1024;

  const int tid = threadIdx.x, w = tid >> 6, lane = tid & 63;
  const int lane15 = lane & 15, quad = lane >> 4;
  const int wm = w >> 1, wn = w & 1;  // 4M x 2N wave grid (64x64 per wave)

  f32x4 acc[4][4];
  {
    f32x4 z_ = {0.f, 0.f, 0.f, 0.f};
#pragma unroll
    for (int i = 0; i < 4; ++i)
#pragma unroll
      for (int j = 0; j < 4; ++j) acc[i][j] = z_;
  }

  // fragment base pointers: 16 rows x 64B segments per load instruction
  const unsigned short* arow = At + (size_t)(wm * 64 + lane15) * 1024 + quad * 8;
  const unsigned short* brow = Bt_ + (size_t)(wn * 64 + lane15) * 1024 + quad * 8;
  auto loadA = [&](bf16x8 af[4], int ko) {
#pragma unroll
    for (int mi = 0; mi < 4; ++mi)
      af[mi] = *(const bf16x8*)(arow + (size_t)(mi * 16) * 1024 + ko * 32);
  };
  auto loadB = [&](bf16x8 bf[4], int ko) {
#pragma unroll
    for (int ni = 0; ni < 4; ++ni)
      bf[ni] = *(const bf16x8*)(brow + (size_t)(ni * 16) * 1024 + ko * 32);
  };
  auto step = [&](const bf16x8 af[4], const bf16x8 bf[4]) {
    __builtin_amdgcn_s_setprio(1);
#pragma unroll
    for (int mi = 0; mi < 4; ++mi)
#pragma unroll
      for (int ni = 0; ni < 4; ++ni)
        acc[mi][ni] = MFMA(af[mi], bf[ni], acc[mi][ni]);
    __builtin_amdgcn_s_setprio(0);
  };

  bf16x8 afA[4], bfA[4], afB[4], bfB[4];
  loadA(afA, 0);
  loadB(bfA, 0);
  for (int t = 0; t < 32; t += 2) {
    if (t + 1 < 32) { loadA(afB, t + 1); loadB(bfB, t + 1); }
    step(afA, bfA);
    if (t + 2 < 32) { loadA(afA, t + 2); loadB(bfA, t + 2); }
    step(afB, bfB);
  }

  // ---- epilogue ----
  const int r0 = tm + wm * 64 + quad * 4;
  const int c0 = tn + wn * 64 + lane15;
  if (z == 0) {
#pragma unroll
    for (int mf = 0; mf < 4; ++mf) {
      const float4 b4 = *(const float4*)&bpre[r0 + mf * 16];
#pragma unroll
      for (int nf = 0; nf < 4; ++nf) {
        const int seq = c0 + nf * 16;
        float vv[4];
#pragma unroll
        for (int rr = 0; rr < 4; ++rr) {
          float v = acc[mf][nf][rr] + ((const float*)&b4)[rr];
          vv[rr] = v / (1.0f + __expf(-v));
        }
        ushort4 pk;
        pk.x = f2bf(vv[0]); pk.y = f2bf(vv[1]);
        pk.z = f2bf(vv[2]); pk.w = f2bf(vv[3]);
        *(ushort4*)&pre[(size_t)seq * 1024 + r0 + mf * 16] = pk;
      }
    }
  } else if (z == 1 || z == 2) {
    unsigned short* dst = (z == 1) ? qb : kb;
#pragma unroll
    for (int mf = 0; mf < 4; ++mf)
#pragma unroll
      for (int nf = 0; nf < 4; ++nf) {
        const int seq = c0 + nf * 16;
        ushort4 pk;
        pk.x = f2bf(acc[mf][nf][0]); pk.y = f2bf(acc[mf][nf][1]);
        pk.z = f2bf(acc[mf][nf][2]); pk.w = f2bf(acc[mf][nf][3]);
        *(ushort4*)&dst[(size_t)seq * 1024 + r0 + mf * 16] = pk;
      }
  } else {
#pragma unroll
    for (int mf = 0; mf < 4; ++mf) {
      const int m = r0 + mf * 16;
      const int bb_ = m >> 10, nseq = m & 1023;
#pragma unroll
      for (int nf = 0; nf < 4; ++nf) {
        const int cg = c0 + nf * 16;
        const int hh = cg >> 6, dd = cg & 63;
        ushort4 pk;
        pk.x = f2bf(acc[mf][nf][0]); pk.y = f2bf(acc[mf][nf][1]);
        pk.z = f2bf(acc[mf][nf][2]); pk.w = f2bf(acc[mf][nf][3]);
        *(ushort4*)&vt[(size_t)(((bb_ * 16 + hh) << 6) + dd) * 1024 + nseq] = pk;
      }
    }
  }
}

// Lg[b][i][j] = (pi*log2e/32) * dot(pre_i, pre_j); symmetric -> store
// lg[col][row] so rr packs into ushort4.
__global__ __launch_bounds__(256) void k_gemm_logits(
    const unsigned short* __restrict__ pre, const float* __restrict__ pi,
    unsigned short* __restrict__ lg) {
  const int bz = blockIdx.z;
  const unsigned short* base = pre + ((size_t)bz << 20);
  const int tm = blockIdx.y * 64, tn = blockIdx.x * 128;
  GEMM_PROLOGUE(2, 4);
  gemm_core_t<2, 4>(base + (size_t)tm * 1024, base + (size_t)tn * 1024, ldsA, ldsB, acc);
  const float sc = pi[0] * (LOG2E / 32.0f);
  GEMM_EPI_IDX(2, 4);
#pragma unroll
  for (int mi = 0; mi < 2; ++mi)
#pragma unroll
    for (int ni = 0; ni < 4; ++ni) {
      const int col = c0 + ni * 16;
      ushort4 pk;
      pk.x = f2bf(acc[mi][ni][0] * sc); pk.y = f2bf(acc[mi][ni][1] * sc);
      pk.z = f2bf(acc[mi][ni][2] * sc); pk.w = f2bf(acc[mi][ni][3] * sc);
      *(ushort4*)&lg[((size_t)bz << 20) + (size_t)col * 1024 + r0 + mi * 16] = pk;
    }
}

// out = ao @ Wproj + bproj + x, computed as C^T -> float4 stores along outdim.
__global__ __launch_bounds__(256) void k_gemm_out(
    const unsigned short* __restrict__ ao, const unsigned short* __restrict__ wtp,
    const float* __restrict__ bproj, const float* __restrict__ xres,
    float* __restrict__ out) {
  const int tm = blockIdx.x * 64, tn = blockIdx.y * 128;
  GEMM_PROLOGUE(2, 4);
  gemm_core_t<2, 4>(wtp + (size_t)tm * 1024, ao + (size_t)tn * 1024, ldsA, ldsB, acc);
  GEMM_EPI_IDX(2, 4);
#pragma unroll
  for (int mi = 0; mi < 2; ++mi) {
    const float4 b4 = *(const float4*)&bproj[r0 + mi * 16];
#pragma unroll
    for (int ni = 0; ni < 4; ++ni) {
      const int seq = c0 + ni * 16;
      const size_t idx = (size_t)seq * 1024 + r0 + mi * 16;
      const float4 rv = *(const float4*)&xres[idx];
      float4 ov;
      ov.x = acc[mi][ni][0] + b4.x + rv.x;
      ov.y = acc[mi][ni][1] + b4.y + rv.y;
      ov.z = acc[mi][ni][2] + b4.z + rv.z;
      ov.w = acc[mi][ni][3] + b4.w + rv.w;
      *(float4*)&out[idx] = ov;
    }
  }
}

// ---------- fused flash attention: S^T = K q^T, O^T = V^T P^T --------------
// 32 q-rows per wave (two 16-q tiles): K/V ds_reads and staging are SHARED
// across the two q-tiles -> 2x MFMA:LDS ratio and two independent
// QK->softmax->PV streams per wave (ILP doubling for the latency chain).
// Block = 4 waves = 128 q; grid 512 (2 blocks/CU). Pipelined 2-phase,
// kv-chunk = 64, K/V double-buffered. P redistribution via permlane16_swap
// (K rows staged with kv bits 3<->4 swapped; lg bias permuted identically).
// Fixed-offset softmax P = exp2(s - SOFT_OFF). XCD swizzle: xcd = b*2 + h/8.
__global__ __launch_bounds__(256, 2) void k_attn(
    const unsigned short* __restrict__ qb, const unsigned short* __restrict__ kb,
    const unsigned short* __restrict__ vt, const unsigned short* __restrict__ lg,
    unsigned short* __restrict__ ao) {
  __shared__ unsigned short ldsK[2 * 64 * 64];  // [buf][row][d] swz ^(row&7)
  __shared__ unsigned short ldsV[2 * 64 * 64];  // [buf][d][kv] swz ^(d&7)
  const int bid = blockIdx.x;
  const int xcd = bid & 7, idx = bid >> 3;  // idx 0..63
  const int b = xcd >> 1, hg = xcd & 1;
  const int h = hg * 8 + (idx >> 3);
  const int q0 = (idx & 7) * 128;
  const int tid = threadIdx.x, w = tid >> 6, lane = tid & 63;
  const int lane15 = lane & 15, quad = lane >> 4;
  const int qw = q0 + w * 32;  // wave owns q rows [qw, qw+32)

  bf16x8 qf[2][2];
#pragma unroll
  for (int qh = 0; qh < 2; ++qh) {
    const unsigned short* qrow =
        qb + (size_t)((b << 10) + qw + qh * 16 + lane15) * 1024 + (h << 6);
    qf[qh][0] = *(const bf16x8*)(qrow + quad * 8);
    qf[qh][1] = *(const bf16x8*)(qrow + 32 + quad * 8);
  }
  const unsigned short* kbase = kb + ((size_t)(b << 10)) * 1024 + (h << 6);
  const unsigned short* vbase = vt + ((size_t)((b * 16 + h) << 6)) * 1024;
  // bias columns permuted to match K-row permutation sigma:
  // C-pos (mi,quad,rr) holds kv = (mi>>1)*32 + (quad>>1)*16 + (mi&1)*8
  //                                 + (quad&1)*4 + rr
  const unsigned short* lgrow =
      lg + ((size_t)b << 20) + (size_t)(qw + lane15) * 1024 +
      (quad >> 1) * 16 + (quad & 1) * 4;  // qh adds 16*1024

  float lcol[2] = {0.f, 0.f};  // per-lane partial sums of P (q = lane15)
  f32x4 o[2][4];  // O^T tiles per q-half: row d = dt*16+quad*4+rr, col q
  {
    f32x4 z_ = {0.f, 0.f, 0.f, 0.f};
#pragma unroll
    for (int qh = 0; qh < 2; ++qh)
#pragma unroll
      for (int nt = 0; nt < 4; ++nt) o[qh][nt] = z_;
  }

  uint2 lgc[2][4], lgn[2][4];

  auto stage = [&](int ch, unsigned short* sK, unsigned short* sV) {
    const int kv0 = ch * 64;
#pragma unroll
    for (int i = 0; i < 2; ++i) {
      const int p = i * 256 + tid;
      const int r = p >> 3, cc = (p & 7) ^ (r & 7);
      // K: LDS row r holds kv sigma(r) = r with bits 3,4 swapped
      const int rk = (r & 0x27) | ((r & 8) << 1) | ((r & 16) >> 1);
      async_lds16(kbase + (size_t)(kv0 + rk) * 1024 + cc * 8,
                  sK + (i * 256 + w * 64) * 8);
      async_lds16(vbase + (size_t)r * 1024 + kv0 + cc * 8,
                  sV + (i * 256 + w * 64) * 8);
    }
  };
  auto lgload = [&](int ch, uint2 dst[2][4]) {
#pragma unroll
    for (int qh = 0; qh < 2; ++qh)
#pragma unroll
      for (int mi = 0; mi < 4; ++mi)
        dst[qh][mi] = *(const uint2*)(lgrow + qh * 16 * 1024 + ch * 64 +
                                      (mi >> 1) * 32 + (mi & 1) * 8);
  };
  auto compute = [&](const unsigned short* sK, const unsigned short* sV) {
    f32x4 s[2][4];
    __builtin_amdgcn_s_setprio(1);
#pragma unroll
    for (int mi = 0; mi < 4; ++mi) {
      const int row = mi * 16 + lane15;
      bf16x8 k0 = *(const bf16x8*)&sK[row * 64 + ((quad ^ (row & 7)) << 3)];
      bf16x8 k1 = *(const bf16x8*)&sK[row * 64 + (((4 + quad) ^ (row & 7)) << 3)];
#pragma unroll
      for (int qh = 0; qh < 2; ++qh) {
        f32x4 t;
        t[0] = __uint_as_float(lgc[qh][mi].x << 16);
        t[1] = __uint_as_float(lgc[qh][mi].x & 0xffff0000u);
        t[2] = __uint_as_float(lgc[qh][mi].y << 16);
        t[3] = __uint_as_float(lgc[qh][mi].y & 0xffff0000u);
        t = MFMA(k0, qf[qh][0], t);
        t = MFMA(k1, qf[qh][1], t);
        s[qh][mi] = t;
      }
    }
    __builtin_amdgcn_s_setprio(0);
    uint2 pk[2][4];
#pragma unroll
    for (int qh = 0; qh < 2; ++qh) {
      float rs = 0.f;
#pragma unroll
      for (int mi = 0; mi < 4; ++mi) {
        const float p0 = __builtin_amdgcn_exp2f(s[qh][mi][0] - SOFT_OFF);
        const float p1 = __builtin_amdgcn_exp2f(s[qh][mi][1] - SOFT_OFF);
        const float p2 = __builtin_amdgcn_exp2f(s[qh][mi][2] - SOFT_OFF);
        const float p3 = __builtin_amdgcn_exp2f(s[qh][mi][3] - SOFT_OFF);
        rs += (p0 + p1) + (p2 + p3);
        pk[qh][mi].x = pack_bf2(p0, p1);
        pk[qh][mi].y = pack_bf2(p2, p3);
      }
      lcol[qh] += rs;
    }

    // O^T += V^T P^T : V frags shared across q-halves; 2 permlane16_swap
    // per (kp,qh) build the B-operand.
#pragma unroll
    for (int kp = 0; kp < 2; ++kp) {
      bf16x8 vf[4];
#pragma unroll
      for (int dt = 0; dt < 4; ++dt) {
        const int d = dt * 16 + lane15;
        vf[dt] = *(const bf16x8*)&sV[d * 64 +
                                     (((kp * 4 + quad) ^ (d & 7)) << 3)];
      }
#pragma unroll
      for (int qh = 0; qh < 2; ++qh) {
        u32x2 rx = __builtin_amdgcn_permlane16_swap(pk[qh][2 * kp].x,
                                                    pk[qh][2 * kp + 1].x, 0, 0);
        u32x2 ry = __builtin_amdgcn_permlane16_swap(pk[qh][2 * kp].y,
                                                    pk[qh][2 * kp + 1].y, 0, 0);
        uint4 bfv;
        bfv.x = rx.x;  // k = quad*8 + (0,1)
        bfv.y = ry.x;  // k = quad*8 + (2,3)
        bfv.z = rx.y;  // k = quad*8 + (4,5)
        bfv.w = ry.y;  // k = quad*8 + (6,7)
        const bf16x8 pf = __builtin_bit_cast(bf16x8, bfv);
        __builtin_amdgcn_s_setprio(1);
#pragma unroll
        for (int dt = 0; dt < 4; ++dt)
          o[qh][dt] = MFMA(vf[dt], pf, o[qh][dt]);
        __builtin_amdgcn_s_setprio(0);
      }
    }
  };

  unsigned short* sK0 = ldsK;
  unsigned short* sK1 = ldsK + 64 * 64;
  unsigned short* sV0 = ldsV;
  unsigned short* sV1 = ldsV + 64 * 64;

  stage(0, sK0, sV0);
  lgload(0, lgc);
  __syncthreads();

  for (int c = 0; c < 16; c += 2) {
    stage(c + 1, sK1, sV1);
    lgload(c + 1, lgn);
    compute(sK0, sV0);
    __syncthreads();
#pragma unroll
    for (int qh = 0; qh < 2; ++qh)
#pragma unroll
      for (int mi = 0; mi < 4; ++mi) lgc[qh][mi] = lgn[qh][mi];
    if (c + 2 < 16) {
      stage(c + 2, sK0, sV0);
      lgload(c + 2, lgn);
    }
    compute(sK1, sV1);
    __syncthreads();
#pragma unroll
    for (int qh = 0; qh < 2; ++qh)
#pragma unroll
      for (int mi = 0; mi < 4; ++mi) lgc[qh][mi] = lgn[qh][mi];
  }

#pragma unroll
  for (int qh = 0; qh < 2; ++qh) {
    float lc = lcol[qh];
    lc += __shfl_xor(lc, 16);
    lc += __shfl_xor(lc, 32);
    const float rinv = 1.0f / lc;
    const int m = (b << 10) + qw + qh * 16 + lane15;
#pragma unroll
    for (int dt = 0; dt < 4; ++dt) {
      ushort4 pkk;
      pkk.x = f2bf(o[qh][dt][0] * rinv);
      pkk.y = f2bf(o[qh][dt][1] * rinv);
      pkk.z = f2bf(o[qh][dt][2] * rinv);
      pkk.w = f2bf(o[qh][dt][3] * rinv);
      *(ushort4*)&ao[(size_t)m * 1024 + (h << 6) + dt * 16 + quad * 4] = pkk;
    }
  }
}

// ---------- launch ----------
extern "C" void kernel_launch(void* const* d_in, const int* in_sizes, int n_in,
                              void* d_out, int out_size, void* d_ws, size_t ws_size,
                              hipStream_t stream) {
  const float* x     = (const float*)d_in[0];
  const float* Wq    = (const float*)d_in[1];
  const float* Wk    = (const float*)d_in[2];
  const float* Wv    = (const float*)d_in[3];
  const float* Wproj = (const float*)d_in[4];
  const float* bproj = (const float*)d_in[5];
  const float* Wpre  = (const float*)d_in[6];
  const float* bpre  = (const float*)d_in[7];
  const float* pi    = (const float*)d_in[8];
  float* out = (float*)d_out;
  char* ws = (char*)d_ws;

  unsigned short* xb  = (unsigned short*)(ws);               // 8 MB (later: lg)
  unsigned short* wt  = (unsigned short*)(ws + (8u << 20));  // 10 MB
  unsigned short* pre = (unsigned short*)(ws + (18u << 20)); // 8 MB (later: ao)
  unsigned short* qb  = (unsigned short*)(ws + (26u << 20)); // 8 MB
  unsigned short* kb  = (unsigned short*)(ws + (34u << 20)); // 8 MB
  unsigned short* vt  = (unsigned short*)(ws + (42u << 20)); // 8 MB
  unsigned short* lg  = xb;   // xb dead after k_gemm_qkvpre
  unsigned short* ao  = pre;  // pre dead after k_gemm_logits

  k_prep<<<dim3(4096 + 5120), dim3(256), 0, stream>>>(
      (const float4*)x, (ushort4*)xb, Wpre, Wq, Wk, Wv, Wproj, wt);
  k_gemm_qkvpre<<<dim3(512), dim3(512), 0, stream>>>(xb, wt, bpre, pre, qb, kb, vt);
  k_gemm_logits<<<dim3(8, 16, 4), dim3(256), 0, stream>>>(pre, pi, lg);
  k_attn<<<dim3(512), dim3(256), 0, stream>>>(qb, kb, vt, lg, ao);
  k_gemm_out<<<dim3(16, 32, 1), dim3(256), 0, stream>>>(ao, wt + 4 * (1u << 20), bproj, x, out);
}

// Round 10
// 217.131 us; speedup vs baseline: 1.3168x; 1.3168x over previous
//
#include <hip/hip_runtime.h>

// ---------- types ----------
using bf16x8 = __attribute__((ext_vector_type(8))) short;
using v8bf   = __attribute__((ext_vector_type(8))) __bf16;
using f32x4  = __attribute__((ext_vector_type(4))) float;
using u32x2  = __attribute__((ext_vector_type(2))) unsigned;
using bf16x2 = __attribute__((ext_vector_type(2))) __bf16;

typedef const __attribute__((address_space(1))) void GASV;
typedef __attribute__((address_space(3))) void LASV;

template <typename V>
__device__ __forceinline__ auto mfma_bf16_impl(V a, V b, f32x4 c, int)
    -> decltype(__builtin_amdgcn_mfma_f32_16x16x32_bf16(a, b, c, 0, 0, 0)) {
  return __builtin_amdgcn_mfma_f32_16x16x32_bf16(a, b, c, 0, 0, 0);
}
template <typename V>
__device__ __forceinline__ f32x4 mfma_bf16_impl(V a, V b, f32x4 c, long) {
  return __builtin_amdgcn_mfma_f32_16x16x32_bf16(
      __builtin_bit_cast(v8bf, a), __builtin_bit_cast(v8bf, b), c, 0, 0, 0);
}
__device__ __forceinline__ f32x4 MFMA(bf16x8 a, bf16x8 b, f32x4 c) {
  return mfma_bf16_impl(a, b, c, 0);
}

__device__ __forceinline__ void async_lds16(const void* g, void* l) {
  __builtin_amdgcn_global_load_lds((GASV*)g, (LASV*)l, 16, 0, 0);
}

__device__ __forceinline__ unsigned short f2bf(float x) {
  unsigned u = __float_as_uint(x);
  u = u + 0x7fffu + ((u >> 16) & 1u);
  return (unsigned short)(u >> 16);
}

// pack two floats to packed bf16 (RNE); compiler emits v_cvt_pk_bf16_f32
__device__ __forceinline__ unsigned pack_bf2(float lo, float hi) {
  bf16x2 t;
  t[0] = (__bf16)lo;
  t[1] = (__bf16)hi;
  return __builtin_bit_cast(unsigned, t);
}

#define LOG2E 1.4426950408889634f
#define SOFT_OFF 14.0f  // fixed softmax offset (exp2 domain)

// ---------- fused prep: x->bf16 cast (bid<4096) + W transposes (bid>=4096) ----
// Wq (z==1) pre-scaled by LOG2E/8 so attention QK^T lands in exp2 domain.
__global__ __launch_bounds__(256) void k_prep(
    const float4* __restrict__ x, ushort4* __restrict__ xb,
    const float* __restrict__ w0, const float* __restrict__ w1,
    const float* __restrict__ w2, const float* __restrict__ w3,
    const float* __restrict__ w4, unsigned short* __restrict__ out) {
  const int bid = blockIdx.x, tid = threadIdx.x;
  if (bid < 4096) {
    const int i = bid * 256 + tid;
    float4 v = x[i];
    ushort4 p;
    p.x = f2bf(v.x); p.y = f2bf(v.y); p.z = f2bf(v.z); p.w = f2bf(v.w);
    xb[i] = p;
    return;
  }
  __shared__ float t[32][33];
  const int tb = bid - 4096;
  const int z = tb >> 10;
  const float* W = (z == 0) ? w0 : (z == 1) ? w1 : (z == 2) ? w2 : (z == 3) ? w3 : w4;
  const float sc = (z == 1) ? (LOG2E / 8.0f) : 1.0f;
  unsigned short* o = out + (size_t)z * (1u << 20);
  const int bx = (tb & 31) * 32, by = ((tb >> 5) & 31) * 32;
  const int tx = tid & 31, ty = tid >> 5;  // 32 x 8
#pragma unroll
  for (int i = 0; i < 4; ++i)
    t[ty + i * 8][tx] = W[(size_t)(by + ty + i * 8) * 1024 + bx + tx];
  __syncthreads();
#pragma unroll
  for (int i = 0; i < 4; ++i)
    o[(size_t)(bx + ty + i * 8) * 1024 + by + tx] = f2bf(t[tx][ty + i * 8] * sc);
}

// ---------- shared 64x128 C^T GEMM core: BK=32, dbuf, stage-ahead ----------
// R6-proven loop shape: stage(t+1) issues BEFORE compute(t), single
// __syncthreads per step (its vmcnt(0) drains loads that a full compute
// phase + 2-blocks/CU TLP has covered). 4 waves (2M x 2N), 32x64 per wave,
// acc 2x4. 64B LDS rows, 16B chunks swizzled ^((row>>1)&3) (0 conflicts).
__device__ __forceinline__ void gemm64x128_core(
    const unsigned short* __restrict__ At, const unsigned short* __restrict__ Bt,
    unsigned short (*ldsA)[64 * 32], unsigned short (*ldsB)[128 * 32],
    f32x4 acc[2][4]) {
  const int tid = threadIdx.x, w = tid >> 6, lane = tid & 63;
  const int lane15 = lane & 15, quad = lane >> 4;
  const int wm = w >> 1, wn = w & 1;
  auto stage = [&](int ko, int buf) {
    {
      const int r = tid >> 2, cc = (tid & 3) ^ ((r >> 1) & 3);
      async_lds16(At + (size_t)r * 1024 + ko * 32 + cc * 8,
                  &ldsA[buf][(w * 64) * 8]);
    }
#pragma unroll
    for (int j = 0; j < 2; ++j) {
      const int p = j * 256 + tid;
      const int r = p >> 2, cc = (p & 3) ^ ((r >> 1) & 3);
      async_lds16(Bt + (size_t)r * 1024 + ko * 32 + cc * 8,
                  &ldsB[buf][(j * 256 + w * 64) * 8]);
    }
  };
  stage(0, 0);
  __syncthreads();
  for (int t = 0; t < 32; ++t) {
    const int buf = t & 1;
    if (t + 1 < 32) stage(t + 1, buf ^ 1);
    const unsigned short* sA = ldsA[buf];
    const unsigned short* sB = ldsB[buf];
    bf16x8 af[2], bf[4];
#pragma unroll
    for (int mi = 0; mi < 2; ++mi) {
      const int row = wm * 32 + mi * 16 + lane15;
      af[mi] = *(const bf16x8*)&sA[row * 32 + ((quad ^ ((row >> 1) & 3)) << 3)];
    }
#pragma unroll
    for (int ni = 0; ni < 4; ++ni) {
      const int row = wn * 64 + ni * 16 + lane15;
      bf[ni] = *(const bf16x8*)&sB[row * 32 + ((quad ^ ((row >> 1) & 3)) << 3)];
    }
    __builtin_amdgcn_s_setprio(1);
#pragma unroll
    for (int mi = 0; mi < 2; ++mi)
#pragma unroll
      for (int ni = 0; ni < 4; ++ni)
        acc[mi][ni] = MFMA(af[mi], bf[ni], acc[mi][ni]);
    __builtin_amdgcn_s_setprio(0);
    __syncthreads();  // vm0: t+1 staged; lgkm+bar: all reads of buf done
  }
}

// ---------- qkv+pre GEMM: 256x128 tile, BK=32, dbuf, 2 blocks/CU -----------
// 512 blocks (2/CU, 16 waves/CU): latency hiding via inter-block TLP (m114).
// (R7-passing version, 47.3us / 727 TF; R8 A-direct and R9 zero-LDS both
// regressed -- fragment-pattern global loads are request-rate-bound.)
__global__ __launch_bounds__(512, 4) void k_gemm_qkvpre(
    const unsigned short* __restrict__ xb, const unsigned short* __restrict__ wt,
    const float* __restrict__ bpre, unsigned short* __restrict__ pre,
    unsigned short* __restrict__ qb, unsigned short* __restrict__ kb,
    unsigned short* __restrict__ vt) {
  __shared__ unsigned short ldsA[2][256 * 32];
  __shared__ unsigned short ldsB[2][128 * 32];
  const int bid = blockIdx.x;
  const int xcd = bid & 7, idx = bid >> 3;  // idx 0..63 per xcd
  const int z = xcd >> 1, half = xcd & 1;
  int tm, tn;
  if (z == 3) {  // v: M = seq (4096), N = out (1024)
    tm = half * 2048 + (idx >> 3) * 256;  // 8 seq-tiles per half
    tn = (idx & 7) * 128;                 // 8 out-tiles
  } else {       // pre/q/k: M = out (1024), N = seq (4096)
    tm = (idx >> 4) * 256;                // 4 out-tiles
    tn = half * 2048 + (idx & 15) * 128;  // 16 seq-tiles per half
  }
  const unsigned short* At =
      (z == 3) ? xb + (size_t)tm * 1024
               : wt + (size_t)z * (1u << 20) + (size_t)tm * 1024;
  const unsigned short* Bt_ =
      (z == 3) ? wt + (size_t)3 * (1u << 20) + (size_t)tn * 1024
               : xb + (size_t)tn * 1024;

  const int tid = threadIdx.x, w = tid >> 6, lane = tid & 63;
  const int lane15 = lane & 15, quad = lane >> 4;
  const int wm = w >> 1, wn = w & 1;  // 4M x 2N wave grid (64x64 per wave)

  f32x4 acc[4][4];
  {
    f32x4 z_ = {0.f, 0.f, 0.f, 0.f};
#pragma unroll
    for (int i = 0; i < 4; ++i)
#pragma unroll
      for (int j = 0; j < 4; ++j) acc[i][j] = z_;
  }

  // stage K-tile ko into buffer buf: A 2 chunks/thread, B 1 chunk/thread
  auto stage = [&](int ko, int buf) {
#pragma unroll
    for (int j = 0; j < 2; ++j) {
      const int p = j * 512 + tid;
      const int r = p >> 2, cc = (p & 3) ^ ((r >> 1) & 3);
      async_lds16(At + (size_t)r * 1024 + ko * 32 + cc * 8,
                  &ldsA[buf][(j * 512 + w * 64) * 8]);
    }
    {
      const int p = tid;
      const int r = p >> 2, cc = (p & 3) ^ ((r >> 1) & 3);
      async_lds16(Bt_ + (size_t)r * 1024 + ko * 32 + cc * 8,
                  &ldsB[buf][(w * 64) * 8]);
    }
  };

  stage(0, 0);
  __syncthreads();
  for (int t = 0; t < 32; ++t) {
    const int buf = t & 1;
    if (t + 1 < 32) stage(t + 1, buf ^ 1);
    const unsigned short* sA = ldsA[buf];
    const unsigned short* sB = ldsB[buf];
    bf16x8 af[4], bf[4];
#pragma unroll
    for (int mi = 0; mi < 4; ++mi) {
      const int row = wm * 64 + mi * 16 + lane15;
      af[mi] = *(const bf16x8*)&sA[row * 32 + ((quad ^ ((row >> 1) & 3)) << 3)];
    }
#pragma unroll
    for (int ni = 0; ni < 4; ++ni) {
      const int row = wn * 64 + ni * 16 + lane15;
      bf[ni] = *(const bf16x8*)&sB[row * 32 + ((quad ^ ((row >> 1) & 3)) << 3)];
    }
    __builtin_amdgcn_s_setprio(1);
#pragma unroll
    for (int mi = 0; mi < 4; ++mi)
#pragma unroll
      for (int ni = 0; ni < 4; ++ni)
        acc[mi][ni] = MFMA(af[mi], bf[ni], acc[mi][ni]);
    __builtin_amdgcn_s_setprio(0);
    __syncthreads();  // vm0: t+1 staged; lgkm+bar: all reads of buf done
  }

  // ---- epilogue ----
  const int r0 = tm + wm * 64 + quad * 4;
  const int c0 = tn + wn * 64 + lane15;
  if (z == 0) {
#pragma unroll
    for (int mf = 0; mf < 4; ++mf) {
      const float4 b4 = *(const float4*)&bpre[r0 + mf * 16];
#pragma unroll
      for (int nf = 0; nf < 4; ++nf) {
        const int seq = c0 + nf * 16;
        float vv[4];
#pragma unroll
        for (int rr = 0; rr < 4; ++rr) {
          float v = acc[mf][nf][rr] + ((const float*)&b4)[rr];
          vv[rr] = v / (1.0f + __expf(-v));
        }
        ushort4 pk;
        pk.x = f2bf(vv[0]); pk.y = f2bf(vv[1]);
        pk.z = f2bf(vv[2]); pk.w = f2bf(vv[3]);
        *(ushort4*)&pre[(size_t)seq * 1024 + r0 + mf * 16] = pk;
      }
    }
  } else if (z == 1 || z == 2) {
    unsigned short* dst = (z == 1) ? qb : kb;
#pragma unroll
    for (int mf = 0; mf < 4; ++mf)
#pragma unroll
      for (int nf = 0; nf < 4; ++nf) {
        const int seq = c0 + nf * 16;
        ushort4 pk;
        pk.x = f2bf(acc[mf][nf][0]); pk.y = f2bf(acc[mf][nf][1]);
        pk.z = f2bf(acc[mf][nf][2]); pk.w = f2bf(acc[mf][nf][3]);
        *(ushort4*)&dst[(size_t)seq * 1024 + r0 + mf * 16] = pk;
      }
  } else {
#pragma unroll
    for (int mf = 0; mf < 4; ++mf) {
      const int m = r0 + mf * 16;
      const int bb_ = m >> 10, nseq = m & 1023;
#pragma unroll
      for (int nf = 0; nf < 4; ++nf) {
        const int cg = c0 + nf * 16;
        const int hh = cg >> 6, dd = cg & 63;
        ushort4 pk;
        pk.x = f2bf(acc[mf][nf][0]); pk.y = f2bf(acc[mf][nf][1]);
        pk.z = f2bf(acc[mf][nf][2]); pk.w = f2bf(acc[mf][nf][3]);
        *(ushort4*)&vt[(size_t)(((bb_ * 16 + hh) << 6) + dd) * 1024 + nseq] = pk;
      }
    }
  }
}

// Lg[b][i][j] = (pi*log2e/32) * dot(pre_i, pre_j); symmetric -> store
// lg[col][row] so rr packs into ushort4. K-loop: R6-style dbuf core
// (old gemm_core_t issued asyncs then immediately drained them at the
// barrier -- the R0-attn stall, now fixed here too).
__global__ __launch_bounds__(256, 2) void k_gemm_logits(
    const unsigned short* __restrict__ pre, const float* __restrict__ pi,
    unsigned short* __restrict__ lg) {
  __shared__ unsigned short ldsA[2][64 * 32];
  __shared__ unsigned short ldsB[2][128 * 32];
  const int bz = blockIdx.z;
  const unsigned short* base = pre + ((size_t)bz << 20);
  const int tm = blockIdx.y * 64, tn = blockIdx.x * 128;
  f32x4 acc[2][4];
  {
    f32x4 z_ = {0.f, 0.f, 0.f, 0.f};
#pragma unroll
    for (int i = 0; i < 2; ++i)
#pragma unroll
      for (int j = 0; j < 4; ++j) acc[i][j] = z_;
  }
  gemm64x128_core(base + (size_t)tm * 1024, base + (size_t)tn * 1024,
                  ldsA, ldsB, acc);
  const float sc = pi[0] * (LOG2E / 32.0f);
  const int tid = threadIdx.x, w = tid >> 6, lane = tid & 63;
  const int lane15 = lane & 15, quad = lane >> 4;
  const int wm = w >> 1, wn = w & 1;
  const int r0 = tm + wm * 32 + quad * 4;
  const int c0 = tn + wn * 64 + lane15;
#pragma unroll
  for (int mi = 0; mi < 2; ++mi)
#pragma unroll
    for (int ni = 0; ni < 4; ++ni) {
      const int col = c0 + ni * 16;
      ushort4 pk;
      pk.x = f2bf(acc[mi][ni][0] * sc); pk.y = f2bf(acc[mi][ni][1] * sc);
      pk.z = f2bf(acc[mi][ni][2] * sc); pk.w = f2bf(acc[mi][ni][3] * sc);
      *(ushort4*)&lg[((size_t)bz << 20) + (size_t)col * 1024 + r0 + mi * 16] = pk;
    }
}

// out = ao @ Wproj + bproj + x, computed as C^T -> float4 stores along outdim.
// Same R6-style dbuf core.
__global__ __launch_bounds__(256, 2) void k_gemm_out(
    const unsigned short* __restrict__ ao, const unsigned short* __restrict__ wtp,
    const float* __restrict__ bproj, const float* __restrict__ xres,
    float* __restrict__ out) {
  __shared__ unsigned short ldsA[2][64 * 32];
  __shared__ unsigned short ldsB[2][128 * 32];
  const int tm = blockIdx.x * 64, tn = blockIdx.y * 128;
  f32x4 acc[2][4];
  {
    f32x4 z_ = {0.f, 0.f, 0.f, 0.f};
#pragma unroll
    for (int i = 0; i < 2; ++i)
#pragma unroll
      for (int j = 0; j < 4; ++j) acc[i][j] = z_;
  }
  gemm64x128_core(wtp + (size_t)tm * 1024, ao + (size_t)tn * 1024,
                  ldsA, ldsB, acc);
  const int tid = threadIdx.x, w = tid >> 6, lane = tid & 63;
  const int lane15 = lane & 15, quad = lane >> 4;
  const int wm = w >> 1, wn = w & 1;
  const int r0 = tm + wm * 32 + quad * 4;
  const int c0 = tn + wn * 64 + lane15;
#pragma unroll
  for (int mi = 0; mi < 2; ++mi) {
    const float4 b4 = *(const float4*)&bproj[r0 + mi * 16];
#pragma unroll
    for (int ni = 0; ni < 4; ++ni) {
      const int seq = c0 + ni * 16;
      const size_t idx = (size_t)seq * 1024 + r0 + mi * 16;
      const float4 rv = *(const float4*)&xres[idx];
      float4 ov;
      ov.x = acc[mi][ni][0] + b4.x + rv.x;
      ov.y = acc[mi][ni][1] + b4.y + rv.y;
      ov.z = acc[mi][ni][2] + b4.z + rv.z;
      ov.w = acc[mi][ni][3] + b4.w + rv.w;
      *(float4*)&out[idx] = ov;
    }
  }
}

// ---------- fused flash attention: S^T = K q^T, O^T = V^T P^T --------------
// 32 q-rows per wave (two 16-q tiles): K/V ds_reads and staging are SHARED
// across the two q-tiles -> 2x MFMA:LDS ratio and two independent
// QK->softmax->PV streams per wave (ILP doubling for the latency chain).
// Block = 4 waves = 128 q; grid 512 (2 blocks/CU). Pipelined 2-phase,
// kv-chunk = 64, K/V double-buffered. P redistribution via permlane16_swap
// (K rows staged with kv bits 3<->4 swapped; lg bias permuted identically).
// Fixed-offset softmax P = exp2(s - SOFT_OFF). XCD swizzle: xcd = b*2 + h/8.
__global__ __launch_bounds__(256, 2) void k_attn(
    const unsigned short* __restrict__ qb, const unsigned short* __restrict__ kb,
    const unsigned short* __restrict__ vt, const unsigned short* __restrict__ lg,
    unsigned short* __restrict__ ao) {
  __shared__ unsigned short ldsK[2 * 64 * 64];  // [buf][row][d] swz ^(row&7)
  __shared__ unsigned short ldsV[2 * 64 * 64];  // [buf][d][kv] swz ^(d&7)
  const int bid = blockIdx.x;
  const int xcd = bid & 7, idx = bid >> 3;  // idx 0..63
  const int b = xcd >> 1, hg = xcd & 1;
  const int h = hg * 8 + (idx >> 3);
  const int q0 = (idx & 7) * 128;
  const int tid = threadIdx.x, w = tid >> 6, lane = tid & 63;
  const int lane15 = lane & 15, quad = lane >> 4;
  const int qw = q0 + w * 32;  // wave owns q rows [qw, qw+32)

  bf16x8 qf[2][2];
#pragma unroll
  for (int qh = 0; qh < 2; ++qh) {
    const unsigned short* qrow =
        qb + (size_t)((b << 10) + qw + qh * 16 + lane15) * 1024 + (h << 6);
    qf[qh][0] = *(const bf16x8*)(qrow + quad * 8);
    qf[qh][1] = *(const bf16x8*)(qrow + 32 + quad * 8);
  }
  const unsigned short* kbase = kb + ((size_t)(b << 10)) * 1024 + (h << 6);
  const unsigned short* vbase = vt + ((size_t)((b * 16 + h) << 6)) * 1024;
  // bias columns permuted to match K-row permutation sigma:
  // C-pos (mi,quad,rr) holds kv = (mi>>1)*32 + (quad>>1)*16 + (mi&1)*8
  //                                 + (quad&1)*4 + rr
  const unsigned short* lgrow =
      lg + ((size_t)b << 20) + (size_t)(qw + lane15) * 1024 +
      (quad >> 1) * 16 + (quad & 1) * 4;  // qh adds 16*1024

  float lcol[2] = {0.f, 0.f};  // per-lane partial sums of P (q = lane15)
  f32x4 o[2][4];  // O^T tiles per q-half: row d = dt*16+quad*4+rr, col q
  {
    f32x4 z_ = {0.f, 0.f, 0.f, 0.f};
#pragma unroll
    for (int qh = 0; qh < 2; ++qh)
#pragma unroll
      for (int nt = 0; nt < 4; ++nt) o[qh][nt] = z_;
  }

  uint2 lgc[2][4], lgn[2][4];

  auto stage = [&](int ch, unsigned short* sK, unsigned short* sV) {
    const int kv0 = ch * 64;
#pragma unroll
    for (int i = 0; i < 2; ++i) {
      const int p = i * 256 + tid;
      const int r = p >> 3, cc = (p & 7) ^ (r & 7);
      // K: LDS row r holds kv sigma(r) = r with bits 3,4 swapped
      const int rk = (r & 0x27) | ((r & 8) << 1) | ((r & 16) >> 1);
      async_lds16(kbase + (size_t)(kv0 + rk) * 1024 + cc * 8,
                  sK + (i * 256 + w * 64) * 8);
      async_lds16(vbase + (size_t)r * 1024 + kv0 + cc * 8,
                  sV + (i * 256 + w * 64) * 8);
    }
  };
  auto lgload = [&](int ch, uint2 dst[2][4]) {
#pragma unroll
    for (int qh = 0; qh < 2; ++qh)
#pragma unroll
      for (int mi = 0; mi < 4; ++mi)
        dst[qh][mi] = *(const uint2*)(lgrow + qh * 16 * 1024 + ch * 64 +
                                      (mi >> 1) * 32 + (mi & 1) * 8);
  };
  auto compute = [&](const unsigned short* sK, const unsigned short* sV) {
    f32x4 s[2][4];
    __builtin_amdgcn_s_setprio(1);
#pragma unroll
    for (int mi = 0; mi < 4; ++mi) {
      const int row = mi * 16 + lane15;
      bf16x8 k0 = *(const bf16x8*)&sK[row * 64 + ((quad ^ (row & 7)) << 3)];
      bf16x8 k1 = *(const bf16x8*)&sK[row * 64 + (((4 + quad) ^ (row & 7)) << 3)];
#pragma unroll
      for (int qh = 0; qh < 2; ++qh) {
        f32x4 t;
        t[0] = __uint_as_float(lgc[qh][mi].x << 16);
        t[1] = __uint_as_float(lgc[qh][mi].x & 0xffff0000u);
        t[2] = __uint_as_float(lgc[qh][mi].y << 16);
        t[3] = __uint_as_float(lgc[qh][mi].y & 0xffff0000u);
        t = MFMA(k0, qf[qh][0], t);
        t = MFMA(k1, qf[qh][1], t);
        s[qh][mi] = t;
      }
    }
    __builtin_amdgcn_s_setprio(0);
    uint2 pk[2][4];
#pragma unroll
    for (int qh = 0; qh < 2; ++qh) {
      float rs = 0.f;
#pragma unroll
      for (int mi = 0; mi < 4; ++mi) {
        const float p0 = __builtin_amdgcn_exp2f(s[qh][mi][0] - SOFT_OFF);
        const float p1 = __builtin_amdgcn_exp2f(s[qh][mi][1] - SOFT_OFF);
        const float p2 = __builtin_amdgcn_exp2f(s[qh][mi][2] - SOFT_OFF);
        const float p3 = __builtin_amdgcn_exp2f(s[qh][mi][3] - SOFT_OFF);
        rs += (p0 + p1) + (p2 + p3);
        pk[qh][mi].x = pack_bf2(p0, p1);
        pk[qh][mi].y = pack_bf2(p2, p3);
      }
      lcol[qh] += rs;
    }

    // O^T += V^T P^T : V frags shared across q-halves; 2 permlane16_swap
    // per (kp,qh) build the B-operand.
#pragma unroll
    for (int kp = 0; kp < 2; ++kp) {
      bf16x8 vf[4];
#pragma unroll
      for (int dt = 0; dt < 4; ++dt) {
        const int d = dt * 16 + lane15;
        vf[dt] = *(const bf16x8*)&sV[d * 64 +
                                     (((kp * 4 + quad) ^ (d & 7)) << 3)];
      }
#pragma unroll
      for (int qh = 0; qh < 2; ++qh) {
        u32x2 rx = __builtin_amdgcn_permlane16_swap(pk[qh][2 * kp].x,
                                                    pk[qh][2 * kp + 1].x, 0, 0);
        u32x2 ry = __builtin_amdgcn_permlane16_swap(pk[qh][2 * kp].y,
                                                    pk[qh][2 * kp + 1].y, 0, 0);
        uint4 bfv;
        bfv.x = rx.x;  // k = quad*8 + (0,1)
        bfv.y = ry.x;  // k = quad*8 + (2,3)
        bfv.z = rx.y;  // k = quad*8 + (4,5)
        bfv.w = ry.y;  // k = quad*8 + (6,7)
        const bf16x8 pf = __builtin_bit_cast(bf16x8, bfv);
        __builtin_amdgcn_s_setprio(1);
#pragma unroll
        for (int dt = 0; dt < 4; ++dt)
          o[qh][dt] = MFMA(vf[dt], pf, o[qh][dt]);
        __builtin_amdgcn_s_setprio(0);
      }
    }
  };

  unsigned short* sK0 = ldsK;
  unsigned short* sK1 = ldsK + 64 * 64;
  unsigned short* sV0 = ldsV;
  unsigned short* sV1 = ldsV + 64 * 64;

  stage(0, sK0, sV0);
  lgload(0, lgc);
  __syncthreads();

  for (int c = 0; c < 16; c += 2) {
    stage(c + 1, sK1, sV1);
    lgload(c + 1, lgn);
    compute(sK0, sV0);
    __syncthreads();
#pragma unroll
    for (int qh = 0; qh < 2; ++qh)
#pragma unroll
      for (int mi = 0; mi < 4; ++mi) lgc[qh][mi] = lgn[qh][mi];
    if (c + 2 < 16) {
      stage(c + 2, sK0, sV0);
      lgload(c + 2, lgn);
    }
    compute(sK1, sV1);
    __syncthreads();
#pragma unroll
    for (int qh = 0; qh < 2; ++qh)
#pragma unroll
      for (int mi = 0; mi < 4; ++mi) lgc[qh][mi] = lgn[qh][mi];
  }

#pragma unroll
  for (int qh = 0; qh < 2; ++qh) {
    float lc = lcol[qh];
    lc += __shfl_xor(lc, 16);
    lc += __shfl_xor(lc, 32);
    const float rinv = 1.0f / lc;
    const int m = (b << 10) + qw + qh * 16 + lane15;
#pragma unroll
    for (int dt = 0; dt < 4; ++dt) {
      ushort4 pkk;
      pkk.x = f2bf(o[qh][dt][0] * rinv);
      pkk.y = f2bf(o[qh][dt][1] * rinv);
      pkk.z = f2bf(o[qh][dt][2] * rinv);
      pkk.w = f2bf(o[qh][dt][3] * rinv);
      *(ushort4*)&ao[(size_t)m * 1024 + (h << 6) + dt * 16 + quad * 4] = pkk;
    }
  }
}

// ---------- launch ----------
extern "C" void kernel_launch(void* const* d_in, const int* in_sizes, int n_in,
                              void* d_out, int out_size, void* d_ws, size_t ws_size,
                              hipStream_t stream) {
  const float* x     = (const float*)d_in[0];
  const float* Wq    = (const float*)d_in[1];
  const float* Wk    = (const float*)d_in[2];
  const float* Wv    = (const float*)d_in[3];
  const float* Wproj = (const float*)d_in[4];
  const float* bproj = (const float*)d_in[5];
  const float* Wpre  = (const float*)d_in[6];
  const float* bpre  = (const float*)d_in[7];
  const float* pi    = (const float*)d_in[8];
  float* out = (float*)d_out;
  char* ws = (char*)d_ws;

  unsigned short* xb  = (unsigned short*)(ws);               // 8 MB (later: lg)
  unsigned short* wt  = (unsigned short*)(ws + (8u << 20));  // 10 MB
  unsigned short* pre = (unsigned short*)(ws + (18u << 20)); // 8 MB (later: ao)
  unsigned short* qb  = (unsigned short*)(ws + (26u << 20)); // 8 MB
  unsigned short* kb  = (unsigned short*)(ws + (34u << 20)); // 8 MB
  unsigned short* vt  = (unsigned short*)(ws + (42u << 20)); // 8 MB
  unsigned short* lg  = xb;   // xb dead after k_gemm_qkvpre
  unsigned short* ao  = pre;  // pre dead after k_gemm_logits

  k_prep<<<dim3(4096 + 5120), dim3(256), 0, stream>>>(
      (const float4*)x, (ushort4*)xb, Wpre, Wq, Wk, Wv, Wproj, wt);
  k_gemm_qkvpre<<<dim3(512), dim3(512), 0, stream>>>(xb, wt, bpre, pre, qb, kb, vt);
  k_gemm_logits<<<dim3(8, 16, 4), dim3(256), 0, stream>>>(pre, pi, lg);
  k_attn<<<dim3(512), dim3(256), 0, stream>>>(qb, kb, vt, lg, ao);
  k_gemm_out<<<dim3(16, 32, 1), dim3(256), 0, stream>>>(ao, wt + 4 * (1u << 20), bproj, x, out);
}

// Round 11
// 207.336 us; speedup vs baseline: 1.3791x; 1.0472x over previous
//
#include <hip/hip_runtime.h>

// ---------- types ----------
using bf16x8 = __attribute__((ext_vector_type(8))) short;
using v8bf   = __attribute__((ext_vector_type(8))) __bf16;
using f32x4  = __attribute__((ext_vector_type(4))) float;
using u32x2  = __attribute__((ext_vector_type(2))) unsigned;
using bf16x2 = __attribute__((ext_vector_type(2))) __bf16;

typedef const __attribute__((address_space(1))) void GASV;
typedef __attribute__((address_space(3))) void LASV;

template <typename V>
__device__ __forceinline__ auto mfma_bf16_impl(V a, V b, f32x4 c, int)
    -> decltype(__builtin_amdgcn_mfma_f32_16x16x32_bf16(a, b, c, 0, 0, 0)) {
  return __builtin_amdgcn_mfma_f32_16x16x32_bf16(a, b, c, 0, 0, 0);
}
template <typename V>
__device__ __forceinline__ f32x4 mfma_bf16_impl(V a, V b, f32x4 c, long) {
  return __builtin_amdgcn_mfma_f32_16x16x32_bf16(
      __builtin_bit_cast(v8bf, a), __builtin_bit_cast(v8bf, b), c, 0, 0, 0);
}
__device__ __forceinline__ f32x4 MFMA(bf16x8 a, bf16x8 b, f32x4 c) {
  return mfma_bf16_impl(a, b, c, 0);
}

__device__ __forceinline__ void async_lds16(const void* g, void* l) {
  __builtin_amdgcn_global_load_lds((GASV*)g, (LASV*)l, 16, 0, 0);
}

__device__ __forceinline__ unsigned short f2bf(float x) {
  unsigned u = __float_as_uint(x);
  u = u + 0x7fffu + ((u >> 16) & 1u);
  return (unsigned short)(u >> 16);
}

// pack two floats to packed bf16 (RNE); compiler emits v_cvt_pk_bf16_f32
__device__ __forceinline__ unsigned pack_bf2(float lo, float hi) {
  bf16x2 t;
  t[0] = (__bf16)lo;
  t[1] = (__bf16)hi;
  return __builtin_bit_cast(unsigned, t);
}

#define LOG2E 1.4426950408889634f
#define SOFT_OFF 14.0f  // fixed softmax offset (exp2 domain)

// ---------- fused prep: x->bf16 cast (bid<4096) + W transposes (bid>=4096) ----
// Wq (z==1) pre-scaled by LOG2E/8 so attention QK^T lands in exp2 domain.
__global__ __launch_bounds__(256) void k_prep(
    const float4* __restrict__ x, ushort4* __restrict__ xb,
    const float* __restrict__ w0, const float* __restrict__ w1,
    const float* __restrict__ w2, const float* __restrict__ w3,
    const float* __restrict__ w4, unsigned short* __restrict__ out) {
  const int bid = blockIdx.x, tid = threadIdx.x;
  if (bid < 4096) {
    const int i = bid * 256 + tid;
    float4 v = x[i];
    ushort4 p;
    p.x = f2bf(v.x); p.y = f2bf(v.y); p.z = f2bf(v.z); p.w = f2bf(v.w);
    xb[i] = p;
    return;
  }
  __shared__ float t[32][33];
  const int tb = bid - 4096;
  const int z = tb >> 10;
  const float* W = (z == 0) ? w0 : (z == 1) ? w1 : (z == 2) ? w2 : (z == 3) ? w3 : w4;
  const float sc = (z == 1) ? (LOG2E / 8.0f) : 1.0f;
  unsigned short* o = out + (size_t)z * (1u << 20);
  const int bx = (tb & 31) * 32, by = ((tb >> 5) & 31) * 32;
  const int tx = tid & 31, ty = tid >> 5;  // 32 x 8
#pragma unroll
  for (int i = 0; i < 4; ++i)
    t[ty + i * 8][tx] = W[(size_t)(by + ty + i * 8) * 1024 + bx + tx];
  __syncthreads();
#pragma unroll
  for (int i = 0; i < 4; ++i)
    o[(size_t)(bx + ty + i * 8) * 1024 + by + tx] = f2bf(t[tx][ty + i * 8] * sc);
}

// ---------- shared 64x128 C^T GEMM core: BK=64, dbuf, stage-ahead ----------
// R10 post-mortem: BK=32 gave only 8 MFMAs/wave between barriers (~64cy to
// cover a ~300cy drain) and regressed vs the old 2-barrier core (16/pair).
// This version keeps the dbuf stage-before-compute ledger and single barrier
// per step but at BK=64: 16 steps x {6 asyncs/thread || 12 ds_read_b128 ||
// 16 MFMAs}/wave. Addressing is bit-identical to the original gemm_core_t
// (128B rows, 16B chunk ^(r&7) swizzle, proven). LDS 48KB -> 2 blocks/CU
// with launch_bounds(256,2); grids of 512 give the m114 TLP pairing.
// Ledger: buf t's frag reads drain (lgkm) at step-t barrier; buf t is only
// overwritten by step t+1's stage -> safe.
__device__ __forceinline__ void gemm64x128_core(
    const unsigned short* __restrict__ At, const unsigned short* __restrict__ Bt,
    unsigned short (*ldsA)[64 * 64], unsigned short (*ldsB)[128 * 64],
    f32x4 acc[2][4]) {
  const int tid = threadIdx.x, w = tid >> 6, lane = tid & 63;
  const int lane15 = lane & 15, quad = lane >> 4;
  const int wm = w >> 1, wn = w & 1;
  auto stage = [&](int ko, int buf) {
#pragma unroll
    for (int j = 0; j < 2; ++j) {
      const int p = j * 256 + tid;
      const int r = p >> 3, cc = (p & 7) ^ (r & 7);
      async_lds16(At + (size_t)r * 1024 + ko * 64 + cc * 8,
                  &ldsA[buf][(j * 256 + w * 64) * 8]);
    }
#pragma unroll
    for (int j = 0; j < 4; ++j) {
      const int p = j * 256 + tid;
      const int r = p >> 3, cc = (p & 7) ^ (r & 7);
      async_lds16(Bt + (size_t)r * 1024 + ko * 64 + cc * 8,
                  &ldsB[buf][(j * 256 + w * 64) * 8]);
    }
  };
  stage(0, 0);
  __syncthreads();
  for (int t = 0; t < 16; ++t) {
    const int buf = t & 1;
    if (t + 1 < 16) stage(t + 1, buf ^ 1);
    const unsigned short* sA = ldsA[buf];
    const unsigned short* sB = ldsB[buf];
    bf16x8 af[2][2], bf[4][2];
#pragma unroll
    for (int mi = 0; mi < 2; ++mi) {
      const int row = wm * 32 + mi * 16 + lane15;
#pragma unroll
      for (int kh = 0; kh < 2; ++kh)
        af[mi][kh] =
            *(const bf16x8*)&sA[row * 64 + (((kh * 4 + quad) ^ (row & 7)) << 3)];
    }
#pragma unroll
    for (int ni = 0; ni < 4; ++ni) {
      const int row = wn * 64 + ni * 16 + lane15;
#pragma unroll
      for (int kh = 0; kh < 2; ++kh)
        bf[ni][kh] =
            *(const bf16x8*)&sB[row * 64 + (((kh * 4 + quad) ^ (row & 7)) << 3)];
    }
    __builtin_amdgcn_s_setprio(1);
#pragma unroll
    for (int mi = 0; mi < 2; ++mi)
#pragma unroll
      for (int ni = 0; ni < 4; ++ni) {
        acc[mi][ni] = MFMA(af[mi][0], bf[ni][0], acc[mi][ni]);
        acc[mi][ni] = MFMA(af[mi][1], bf[ni][1], acc[mi][ni]);
      }
    __builtin_amdgcn_s_setprio(0);
    __syncthreads();  // vm0: t+1 staged; lgkm+bar: all reads of buf done
  }
}

// ---------- qkv+pre GEMM: 256x128 tile, BK=32, dbuf, 2 blocks/CU -----------
// 512 blocks (2/CU, 16 waves/CU): latency hiding via inter-block TLP (m114).
// (R7-passing version, 47.3us / 727 TF; R8 A-direct and R9 zero-LDS both
// regressed -- fragment-pattern global loads are request-rate-bound.)
__global__ __launch_bounds__(512, 4) void k_gemm_qkvpre(
    const unsigned short* __restrict__ xb, const unsigned short* __restrict__ wt,
    const float* __restrict__ bpre, unsigned short* __restrict__ pre,
    unsigned short* __restrict__ qb, unsigned short* __restrict__ kb,
    unsigned short* __restrict__ vt) {
  __shared__ unsigned short ldsA[2][256 * 32];
  __shared__ unsigned short ldsB[2][128 * 32];
  const int bid = blockIdx.x;
  const int xcd = bid & 7, idx = bid >> 3;  // idx 0..63 per xcd
  const int z = xcd >> 1, half = xcd & 1;
  int tm, tn;
  if (z == 3) {  // v: M = seq (4096), N = out (1024)
    tm = half * 2048 + (idx >> 3) * 256;  // 8 seq-tiles per half
    tn = (idx & 7) * 128;                 // 8 out-tiles
  } else {       // pre/q/k: M = out (1024), N = seq (4096)
    tm = (idx >> 4) * 256;                // 4 out-tiles
    tn = half * 2048 + (idx & 15) * 128;  // 16 seq-tiles per half
  }
  const unsigned short* At =
      (z == 3) ? xb + (size_t)tm * 1024
               : wt + (size_t)z * (1u << 20) + (size_t)tm * 1024;
  const unsigned short* Bt_ =
      (z == 3) ? wt + (size_t)3 * (1u << 20) + (size_t)tn * 1024
               : xb + (size_t)tn * 1024;

  const int tid = threadIdx.x, w = tid >> 6, lane = tid & 63;
  const int lane15 = lane & 15, quad = lane >> 4;
  const int wm = w >> 1, wn = w & 1;  // 4M x 2N wave grid (64x64 per wave)

  f32x4 acc[4][4];
  {
    f32x4 z_ = {0.f, 0.f, 0.f, 0.f};
#pragma unroll
    for (int i = 0; i < 4; ++i)
#pragma unroll
      for (int j = 0; j < 4; ++j) acc[i][j] = z_;
  }

  // stage K-tile ko into buffer buf: A 2 chunks/thread, B 1 chunk/thread
  auto stage = [&](int ko, int buf) {
#pragma unroll
    for (int j = 0; j < 2; ++j) {
      const int p = j * 512 + tid;
      const int r = p >> 2, cc = (p & 3) ^ ((r >> 1) & 3);
      async_lds16(At + (size_t)r * 1024 + ko * 32 + cc * 8,
                  &ldsA[buf][(j * 512 + w * 64) * 8]);
    }
    {
      const int p = tid;
      const int r = p >> 2, cc = (p & 3) ^ ((r >> 1) & 3);
      async_lds16(Bt_ + (size_t)r * 1024 + ko * 32 + cc * 8,
                  &ldsB[buf][(w * 64) * 8]);
    }
  };

  stage(0, 0);
  __syncthreads();
  for (int t = 0; t < 32; ++t) {
    const int buf = t & 1;
    if (t + 1 < 32) stage(t + 1, buf ^ 1);
    const unsigned short* sA = ldsA[buf];
    const unsigned short* sB = ldsB[buf];
    bf16x8 af[4], bf[4];
#pragma unroll
    for (int mi = 0; mi < 4; ++mi) {
      const int row = wm * 64 + mi * 16 + lane15;
      af[mi] = *(const bf16x8*)&sA[row * 32 + ((quad ^ ((row >> 1) & 3)) << 3)];
    }
#pragma unroll
    for (int ni = 0; ni < 4; ++ni) {
      const int row = wn * 64 + ni * 16 + lane15;
      bf[ni] = *(const bf16x8*)&sB[row * 32 + ((quad ^ ((row >> 1) & 3)) << 3)];
    }
    __builtin_amdgcn_s_setprio(1);
#pragma unroll
    for (int mi = 0; mi < 4; ++mi)
#pragma unroll
      for (int ni = 0; ni < 4; ++ni)
        acc[mi][ni] = MFMA(af[mi], bf[ni], acc[mi][ni]);
    __builtin_amdgcn_s_setprio(0);
    __syncthreads();  // vm0: t+1 staged; lgkm+bar: all reads of buf done
  }

  // ---- epilogue ----
  const int r0 = tm + wm * 64 + quad * 4;
  const int c0 = tn + wn * 64 + lane15;
  if (z == 0) {
#pragma unroll
    for (int mf = 0; mf < 4; ++mf) {
      const float4 b4 = *(const float4*)&bpre[r0 + mf * 16];
#pragma unroll
      for (int nf = 0; nf < 4; ++nf) {
        const int seq = c0 + nf * 16;
        float vv[4];
#pragma unroll
        for (int rr = 0; rr < 4; ++rr) {
          float v = acc[mf][nf][rr] + ((const float*)&b4)[rr];
          vv[rr] = v / (1.0f + __expf(-v));
        }
        ushort4 pk;
        pk.x = f2bf(vv[0]); pk.y = f2bf(vv[1]);
        pk.z = f2bf(vv[2]); pk.w = f2bf(vv[3]);
        *(ushort4*)&pre[(size_t)seq * 1024 + r0 + mf * 16] = pk;
      }
    }
  } else if (z == 1 || z == 2) {
    unsigned short* dst = (z == 1) ? qb : kb;
#pragma unroll
    for (int mf = 0; mf < 4; ++mf)
#pragma unroll
      for (int nf = 0; nf < 4; ++nf) {
        const int seq = c0 + nf * 16;
        ushort4 pk;
        pk.x = f2bf(acc[mf][nf][0]); pk.y = f2bf(acc[mf][nf][1]);
        pk.z = f2bf(acc[mf][nf][2]); pk.w = f2bf(acc[mf][nf][3]);
        *(ushort4*)&dst[(size_t)seq * 1024 + r0 + mf * 16] = pk;
      }
  } else {
#pragma unroll
    for (int mf = 0; mf < 4; ++mf) {
      const int m = r0 + mf * 16;
      const int bb_ = m >> 10, nseq = m & 1023;
#pragma unroll
      for (int nf = 0; nf < 4; ++nf) {
        const int cg = c0 + nf * 16;
        const int hh = cg >> 6, dd = cg & 63;
        ushort4 pk;
        pk.x = f2bf(acc[mf][nf][0]); pk.y = f2bf(acc[mf][nf][1]);
        pk.z = f2bf(acc[mf][nf][2]); pk.w = f2bf(acc[mf][nf][3]);
        *(ushort4*)&vt[(size_t)(((bb_ * 16 + hh) << 6) + dd) * 1024 + nseq] = pk;
      }
    }
  }
}

// Lg[b][i][j] = (pi*log2e/32) * dot(pre_i, pre_j); symmetric -> store
// lg[col][row] so rr packs into ushort4. K-loop: BK=64 dbuf stage-ahead core.
__global__ __launch_bounds__(256, 2) void k_gemm_logits(
    const unsigned short* __restrict__ pre, const float* __restrict__ pi,
    unsigned short* __restrict__ lg) {
  __shared__ unsigned short ldsA[2][64 * 64];
  __shared__ unsigned short ldsB[2][128 * 64];
  const int bz = blockIdx.z;
  const unsigned short* base = pre + ((size_t)bz << 20);
  const int tm = blockIdx.y * 64, tn = blockIdx.x * 128;
  f32x4 acc[2][4];
  {
    f32x4 z_ = {0.f, 0.f, 0.f, 0.f};
#pragma unroll
    for (int i = 0; i < 2; ++i)
#pragma unroll
      for (int j = 0; j < 4; ++j) acc[i][j] = z_;
  }
  gemm64x128_core(base + (size_t)tm * 1024, base + (size_t)tn * 1024,
                  ldsA, ldsB, acc);
  const float sc = pi[0] * (LOG2E / 32.0f);
  const int tid = threadIdx.x, w = tid >> 6, lane = tid & 63;
  const int lane15 = lane & 15, quad = lane >> 4;
  const int wm = w >> 1, wn = w & 1;
  const int r0 = tm + wm * 32 + quad * 4;
  const int c0 = tn + wn * 64 + lane15;
#pragma unroll
  for (int mi = 0; mi < 2; ++mi)
#pragma unroll
    for (int ni = 0; ni < 4; ++ni) {
      const int col = c0 + ni * 16;
      ushort4 pk;
      pk.x = f2bf(acc[mi][ni][0] * sc); pk.y = f2bf(acc[mi][ni][1] * sc);
      pk.z = f2bf(acc[mi][ni][2] * sc); pk.w = f2bf(acc[mi][ni][3] * sc);
      *(ushort4*)&lg[((size_t)bz << 20) + (size_t)col * 1024 + r0 + mi * 16] = pk;
    }
}

// out = ao @ Wproj + bproj + x, computed as C^T -> float4 stores along outdim.
// Same BK=64 dbuf stage-ahead core.
__global__ __launch_bounds__(256, 2) void k_gemm_out(
    const unsigned short* __restrict__ ao, const unsigned short* __restrict__ wtp,
    const float* __restrict__ bproj, const float* __restrict__ xres,
    float* __restrict__ out) {
  __shared__ unsigned short ldsA[2][64 * 64];
  __shared__ unsigned short ldsB[2][128 * 64];
  const int tm = blockIdx.x * 64, tn = blockIdx.y * 128;
  f32x4 acc[2][4];
  {
    f32x4 z_ = {0.f, 0.f, 0.f, 0.f};
#pragma unroll
    for (int i = 0; i < 2; ++i)
#pragma unroll
      for (int j = 0; j < 4; ++j) acc[i][j] = z_;
  }
  gemm64x128_core(wtp + (size_t)tm * 1024, ao + (size_t)tn * 1024,
                  ldsA, ldsB, acc);
  const int tid = threadIdx.x, w = tid >> 6, lane = tid & 63;
  const int lane15 = lane & 15, quad = lane >> 4;
  const int wm = w >> 1, wn = w & 1;
  const int r0 = tm + wm * 32 + quad * 4;
  const int c0 = tn + wn * 64 + lane15;
#pragma unroll
  for (int mi = 0; mi < 2; ++mi) {
    const float4 b4 = *(const float4*)&bproj[r0 + mi * 16];
#pragma unroll
    for (int ni = 0; ni < 4; ++ni) {
      const int seq = c0 + ni * 16;
      const size_t idx = (size_t)seq * 1024 + r0 + mi * 16;
      const float4 rv = *(const float4*)&xres[idx];
      float4 ov;
      ov.x = acc[mi][ni][0] + b4.x + rv.x;
      ov.y = acc[mi][ni][1] + b4.y + rv.y;
      ov.z = acc[mi][ni][2] + b4.z + rv.z;
      ov.w = acc[mi][ni][3] + b4.w + rv.w;
      *(float4*)&out[idx] = ov;
    }
  }
}

// ---------- fused flash attention: S^T = K q^T, O^T = V^T P^T --------------
// 32 q-rows per wave (two 16-q tiles): K/V ds_reads and staging are SHARED
// across the two q-tiles -> 2x MFMA:LDS ratio and two independent
// QK->softmax->PV streams per wave (ILP doubling for the latency chain).
// Block = 4 waves = 128 q; grid 512 (2 blocks/CU). Pipelined 2-phase,
// kv-chunk = 64, K/V double-buffered. P redistribution via permlane16_swap
// (K rows staged with kv bits 3<->4 swapped; lg bias permuted identically).
// Fixed-offset softmax P = exp2(s - SOFT_OFF). XCD swizzle: xcd = b*2 + h/8.
__global__ __launch_bounds__(256, 2) void k_attn(
    const unsigned short* __restrict__ qb, const unsigned short* __restrict__ kb,
    const unsigned short* __restrict__ vt, const unsigned short* __restrict__ lg,
    unsigned short* __restrict__ ao) {
  __shared__ unsigned short ldsK[2 * 64 * 64];  // [buf][row][d] swz ^(row&7)
  __shared__ unsigned short ldsV[2 * 64 * 64];  // [buf][d][kv] swz ^(d&7)
  const int bid = blockIdx.x;
  const int xcd = bid & 7, idx = bid >> 3;  // idx 0..63
  const int b = xcd >> 1, hg = xcd & 1;
  const int h = hg * 8 + (idx >> 3);
  const int q0 = (idx & 7) * 128;
  const int tid = threadIdx.x, w = tid >> 6, lane = tid & 63;
  const int lane15 = lane & 15, quad = lane >> 4;
  const int qw = q0 + w * 32;  // wave owns q rows [qw, qw+32)

  bf16x8 qf[2][2];
#pragma unroll
  for (int qh = 0; qh < 2; ++qh) {
    const unsigned short* qrow =
        qb + (size_t)((b << 10) + qw + qh * 16 + lane15) * 1024 + (h << 6);
    qf[qh][0] = *(const bf16x8*)(qrow + quad * 8);
    qf[qh][1] = *(const bf16x8*)(qrow + 32 + quad * 8);
  }
  const unsigned short* kbase = kb + ((size_t)(b << 10)) * 1024 + (h << 6);
  const unsigned short* vbase = vt + ((size_t)((b * 16 + h) << 6)) * 1024;
  // bias columns permuted to match K-row permutation sigma:
  // C-pos (mi,quad,rr) holds kv = (mi>>1)*32 + (quad>>1)*16 + (mi&1)*8
  //                                 + (quad&1)*4 + rr
  const unsigned short* lgrow =
      lg + ((size_t)b << 20) + (size_t)(qw + lane15) * 1024 +
      (quad >> 1) * 16 + (quad & 1) * 4;  // qh adds 16*1024

  float lcol[2] = {0.f, 0.f};  // per-lane partial sums of P (q = lane15)
  f32x4 o[2][4];  // O^T tiles per q-half: row d = dt*16+quad*4+rr, col q
  {
    f32x4 z_ = {0.f, 0.f, 0.f, 0.f};
#pragma unroll
    for (int qh = 0; qh < 2; ++qh)
#pragma unroll
      for (int nt = 0; nt < 4; ++nt) o[qh][nt] = z_;
  }

  uint2 lgc[2][4], lgn[2][4];

  auto stage = [&](int ch, unsigned short* sK, unsigned short* sV) {
    const int kv0 = ch * 64;
#pragma unroll
    for (int i = 0; i < 2; ++i) {
      const int p = i * 256 + tid;
      const int r = p >> 3, cc = (p & 7) ^ (r & 7);
      // K: LDS row r holds kv sigma(r) = r with bits 3,4 swapped
      const int rk = (r & 0x27) | ((r & 8) << 1) | ((r & 16) >> 1);
      async_lds16(kbase + (size_t)(kv0 + rk) * 1024 + cc * 8,
                  sK + (i * 256 + w * 64) * 8);
      async_lds16(vbase + (size_t)r * 1024 + kv0 + cc * 8,
                  sV + (i * 256 + w * 64) * 8);
    }
  };
  auto lgload = [&](int ch, uint2 dst[2][4]) {
#pragma unroll
    for (int qh = 0; qh < 2; ++qh)
#pragma unroll
      for (int mi = 0; mi < 4; ++mi)
        dst[qh][mi] = *(const uint2*)(lgrow + qh * 16 * 1024 + ch * 64 +
                                      (mi >> 1) * 32 + (mi & 1) * 8);
  };
  auto compute = [&](const unsigned short* sK, const unsigned short* sV) {
    f32x4 s[2][4];
    __builtin_amdgcn_s_setprio(1);
#pragma unroll
    for (int mi = 0; mi < 4; ++mi) {
      const int row = mi * 16 + lane15;
      bf16x8 k0 = *(const bf16x8*)&sK[row * 64 + ((quad ^ (row & 7)) << 3)];
      bf16x8 k1 = *(const bf16x8*)&sK[row * 64 + (((4 + quad) ^ (row & 7)) << 3)];
#pragma unroll
      for (int qh = 0; qh < 2; ++qh) {
        f32x4 t;
        t[0] = __uint_as_float(lgc[qh][mi].x << 16);
        t[1] = __uint_as_float(lgc[qh][mi].x & 0xffff0000u);
        t[2] = __uint_as_float(lgc[qh][mi].y << 16);
        t[3] = __uint_as_float(lgc[qh][mi].y & 0xffff0000u);
        t = MFMA(k0, qf[qh][0], t);
        t = MFMA(k1, qf[qh][1], t);
        s[qh][mi] = t;
      }
    }
    __builtin_amdgcn_s_setprio(0);
    uint2 pk[2][4];
#pragma unroll
    for (int qh = 0; qh < 2; ++qh) {
      float rs = 0.f;
#pragma unroll
      for (int mi = 0; mi < 4; ++mi) {
        const float p0 = __builtin_amdgcn_exp2f(s[qh][mi][0] - SOFT_OFF);
        const float p1 = __builtin_amdgcn_exp2f(s[qh][mi][1] - SOFT_OFF);
        const float p2 = __builtin_amdgcn_exp2f(s[qh][mi][2] - SOFT_OFF);
        const float p3 = __builtin_amdgcn_exp2f(s[qh][mi][3] - SOFT_OFF);
        rs += (p0 + p1) + (p2 + p3);
        pk[qh][mi].x = pack_bf2(p0, p1);
        pk[qh][mi].y = pack_bf2(p2, p3);
      }
      lcol[qh] += rs;
    }

    // O^T += V^T P^T : V frags shared across q-halves; 2 permlane16_swap
    // per (kp,qh) build the B-operand.
#pragma unroll
    for (int kp = 0; kp < 2; ++kp) {
      bf16x8 vf[4];
#pragma unroll
      for (int dt = 0; dt < 4; ++dt) {
        const int d = dt * 16 + lane15;
        vf[dt] = *(const bf16x8*)&sV[d * 64 +
                                     (((kp * 4 + quad) ^ (d & 7)) << 3)];
      }
#pragma unroll
      for (int qh = 0; qh < 2; ++qh) {
        u32x2 rx = __builtin_amdgcn_permlane16_swap(pk[qh][2 * kp].x,
                                                    pk[qh][2 * kp + 1].x, 0, 0);
        u32x2 ry = __builtin_amdgcn_permlane16_swap(pk[qh][2 * kp].y,
                                                    pk[qh][2 * kp + 1].y, 0, 0);
        uint4 bfv;
        bfv.x = rx.x;  // k = quad*8 + (0,1)
        bfv.y = ry.x;  // k = quad*8 + (2,3)
        bfv.z = rx.y;  // k = quad*8 + (4,5)
        bfv.w = ry.y;  // k = quad*8 + (6,7)
        const bf16x8 pf = __builtin_bit_cast(bf16x8, bfv);
        __builtin_amdgcn_s_setprio(1);
#pragma unroll
        for (int dt = 0; dt < 4; ++dt)
          o[qh][dt] = MFMA(vf[dt], pf, o[qh][dt]);
        __builtin_amdgcn_s_setprio(0);
      }
    }
  };

  unsigned short* sK0 = ldsK;
  unsigned short* sK1 = ldsK + 64 * 64;
  unsigned short* sV0 = ldsV;
  unsigned short* sV1 = ldsV + 64 * 64;

  stage(0, sK0, sV0);
  lgload(0, lgc);
  __syncthreads();

  for (int c = 0; c < 16; c += 2) {
    stage(c + 1, sK1, sV1);
    lgload(c + 1, lgn);
    compute(sK0, sV0);
    __syncthreads();
#pragma unroll
    for (int qh = 0; qh < 2; ++qh)
#pragma unroll
      for (int mi = 0; mi < 4; ++mi) lgc[qh][mi] = lgn[qh][mi];
    if (c + 2 < 16) {
      stage(c + 2, sK0, sV0);
      lgload(c + 2, lgn);
    }
    compute(sK1, sV1);
    __syncthreads();
#pragma unroll
    for (int qh = 0; qh < 2; ++qh)
#pragma unroll
      for (int mi = 0; mi < 4; ++mi) lgc[qh][mi] = lgn[qh][mi];
  }

#pragma unroll
  for (int qh = 0; qh < 2; ++qh) {
    float lc = lcol[qh];
    lc += __shfl_xor(lc, 16);
    lc += __shfl_xor(lc, 32);
    const float rinv = 1.0f / lc;
    const int m = (b << 10) + qw + qh * 16 + lane15;
#pragma unroll
    for (int dt = 0; dt < 4; ++dt) {
      ushort4 pkk;
      pkk.x = f2bf(o[qh][dt][0] * rinv);
      pkk.y = f2bf(o[qh][dt][1] * rinv);
      pkk.z = f2bf(o[qh][dt][2] * rinv);
      pkk.w = f2bf(o[qh][dt][3] * rinv);
      *(ushort4*)&ao[(size_t)m * 1024 + (h << 6) + dt * 16 + quad * 4] = pkk;
    }
  }
}

// ---------- launch ----------
extern "C" void kernel_launch(void* const* d_in, const int* in_sizes, int n_in,
                              void* d_out, int out_size, void* d_ws, size_t ws_size,
                              hipStream_t stream) {
  const float* x     = (const float*)d_in[0];
  const float* Wq    = (const float*)d_in[1];
  const float* Wk    = (const float*)d_in[2];
  const float* Wv    = (const float*)d_in[3];
  const float* Wproj = (const float*)d_in[4];
  const float* bproj = (const float*)d_in[5];
  const float* Wpre  = (const float*)d_in[6];
  const float* bpre  = (const float*)d_in[7];
  const float* pi    = (const float*)d_in[8];
  float* out = (float*)d_out;
  char* ws = (char*)d_ws;

  unsigned short* xb  = (unsigned short*)(ws);               // 8 MB (later: lg)
  unsigned short* wt  = (unsigned short*)(ws + (8u << 20));  // 10 MB
  unsigned short* pre = (unsigned short*)(ws + (18u << 20)); // 8 MB (later: ao)
  unsigned short* qb  = (unsigned short*)(ws + (26u << 20)); // 8 MB
  unsigned short* kb  = (unsigned short*)(ws + (34u << 20)); // 8 MB
  unsigned short* vt  = (unsigned short*)(ws + (42u << 20)); // 8 MB
  unsigned short* lg  = xb;   // xb dead after k_gemm_qkvpre
  unsigned short* ao  = pre;  // pre dead after k_gemm_logits

  k_prep<<<dim3(4096 + 5120), dim3(256), 0, stream>>>(
      (const float4*)x, (ushort4*)xb, Wpre, Wq, Wk, Wv, Wproj, wt);
  k_gemm_qkvpre<<<dim3(512), dim3(512), 0, stream>>>(xb, wt, bpre, pre, qb, kb, vt);
  k_gemm_logits<<<dim3(8, 16, 4), dim3(256), 0, stream>>>(pre, pi, lg);
  k_attn<<<dim3(512), dim3(256), 0, stream>>>(qb, kb, vt, lg, ao);
  k_gemm_out<<<dim3(16, 32, 1), dim3(256), 0, stream>>>(ao, wt + 4 * (1u << 20), bproj, x, out);
}